// Round 1
// baseline (2695.593 us; speedup 1.0000x reference)
//
#include <hip/hip_runtime.h>

#define HIDN 128
#define FEATN 128
#define TN 64
#define BN 2048
#define G 4            // batch elems per block
#define NBLK (BN/G)    // 512 blocks -> 2 blocks/CU @ ~48KB LDS

__device__ __forceinline__ float fast_tanh(float x) {
    x = fminf(15.f, fmaxf(-15.f, x));
    float t = __expf(2.f * x);
    return 1.f - 2.f / (t + 1.f);
}
__device__ __forceinline__ float fast_sigmoid(float x) {
    return 1.f / (1.f + __expf(-x));
}

// Kernel A1: HW[b,t,f] = H[b,t,:] @ W1[256:384,:] + b1[f]   (time-invariant part)
__global__ __launch_bounds__(256) void precompute_hw(
    const float* __restrict__ H, const float* __restrict__ W1,
    const float* __restrict__ b1, float* __restrict__ HW) {
    __shared__ float sH[16 * 128];
    const int i = threadIdx.x;
    const long r0 = (long)blockIdx.x * 16;   // 16 rows of [B*T, 128] per block
    #pragma unroll
    for (int u = 0; u < 8; ++u) {
        int idx = u * 256 + i;
        sH[idx] = H[r0 * 128 + idx];
    }
    __syncthreads();
    const int f = i & 127;
    const int half = i >> 7;
    float acc[8];
    float bb = b1[f];
    #pragma unroll
    for (int u = 0; u < 8; ++u) acc[u] = bb;
    #pragma unroll 4
    for (int h = 0; h < 128; ++h) {
        float wv = W1[(256 + h) * 128 + f];
        #pragma unroll
        for (int u = 0; u < 8; ++u)
            acc[u] = fmaf(sH[(half + 2 * u) * 128 + h], wv, acc[u]);
    }
    #pragma unroll
    for (int u = 0; u < 8; ++u) {
        int rr = half + 2 * u;
        HW[(r0 + rr) * 128 + f] = acc[u];
    }
}

// Kernel A2: W_hhT[k][j] = W_hh[j][k]  (coalesced weight reads in the scan)
__global__ __launch_bounds__(256) void transpose_whh(
    const float* __restrict__ Whh, float* __restrict__ WT) {
    int tid = blockIdx.x * 256 + threadIdx.x;
    int j = tid & 511;
    int k = tid >> 9;
    WT[k * 512 + j] = Whh[j * 128 + k];
}

// Kernel B: persistent scan. One block owns G=4 batch elements for all 64 steps.
__global__ __launch_bounds__(256) void decoder_scan(
    const float* __restrict__ H, const float* __restrict__ Y,
    const float* __restrict__ W1, const float* __restrict__ W2,
    const float* __restrict__ Wih, const float* __restrict__ bih,
    const float* __restrict__ bhh, const float* __restrict__ fcW,
    const float* __restrict__ fcb, const float* __restrict__ fcfW,
    const float* __restrict__ fcfb,
    const float* __restrict__ HW, const float* __restrict__ WT,
    float* __restrict__ out) {

    __shared__ float sTile[64 * 132];   // padded HW tile (stride 132)
    __shared__ float sdc[G][256];       // [d | c] per batch elem
    __shared__ float sctx[G][128];
    __shared__ float sp[G][128];
    __shared__ float sbeta[G][64];      // e then beta
    __shared__ float sy[G];
    __shared__ float sW2[128];
    __shared__ float sfcW[129];
    __shared__ float sWih[512];
    __shared__ float sbsum[512];

    const int i = threadIdx.x;
    const int bbase = blockIdx.x * G;
    const int f = i & 127;
    const int gg = i >> 7;   // 0/1
    const int wv_id = i >> 6; // wave 0..3
    const int l = i & 63;

    // init
    for (int u = i; u < G * 256; u += 256) ((float*)sdc)[u] = 0.f;
    if (i < 128) sW2[i] = W2[i];
    if (i < 129) sfcW[i] = fcW[i];
    sWih[i] = Wih[i];
    sWih[i + 256] = Wih[i + 256];
    sbsum[i] = bih[i] + bhh[i];
    sbsum[i + 256] = bih[i + 256] + bhh[i + 256];
    __syncthreads();

    for (int t = 0; t < TN; ++t) {
        // ---- phase 1: p = dc @ W1[0:256,:]  (2 batch elems per thread) ----
        float p0 = 0.f, p1 = 0.f;
        #pragma unroll 4
        for (int j = 0; j < 256; ++j) {
            float wv = W1[j * 128 + f];
            p0 = fmaf(sdc[gg][j], wv, p0);
            p1 = fmaf(sdc[gg + 2][j], wv, p1);
        }
        sp[gg][f] = p0;
        sp[gg + 2][f] = p1;
        __syncthreads();

        // ---- phase 2: e[g][t'] = sum_f tanh(HW + p) * W2 ----
        for (int g = 0; g < G; ++g) {
            const float* hwb = HW + (long)(bbase + g) * (TN * 128);
            #pragma unroll
            for (int u = 0; u < 32; ++u) {
                int idx = u * 256 + i;
                sTile[(idx >> 7) * 132 + (idx & 127)] = hwb[idx];
            }
            __syncthreads();
            int tt = i >> 2, q = i & 3;
            float acc = 0.f;
            #pragma unroll 8
            for (int s = 0; s < 32; ++s) {
                int ff = q + 4 * s;
                float v = sTile[tt * 132 + ff] + sp[g][ff];
                acc = fmaf(fast_tanh(v), sW2[ff], acc);
            }
            acc += __shfl_xor(acc, 1);
            acc += __shfl_xor(acc, 2);
            if (q == 0) sbeta[g][tt] = acc;
            __syncthreads();
        }

        // ---- phase 3: softmax over T, wave w handles g=w ----
        {
            int g = wv_id;
            float e = sbeta[g][l];
            float m = e;
            #pragma unroll
            for (int d = 1; d < 64; d <<= 1) m = fmaxf(m, __shfl_xor(m, d));
            float ex = __expf(e - m);
            float s = ex;
            #pragma unroll
            for (int d = 1; d < 64; d <<= 1) s += __shfl_xor(s, d);
            sbeta[g][l] = ex / s;
        }
        __syncthreads();

        // ---- phase 4: context[g][h] = sum_t beta * H ----
        {
            float c0 = 0.f, c1 = 0.f;
            const float* h0 = H + (long)(bbase + gg) * (TN * 128) + f;
            const float* h1 = H + (long)(bbase + gg + 2) * (TN * 128) + f;
            #pragma unroll 8
            for (int tt2 = 0; tt2 < TN; ++tt2) {
                c0 = fmaf(sbeta[gg][tt2], h0[tt2 * 128], c0);
                c1 = fmaf(sbeta[gg + 2][tt2], h1[tt2 * 128], c1);
            }
            sctx[gg][f] = c0;
            sctx[gg + 2][f] = c1;
        }
        __syncthreads();

        // ---- phase 5: y_tilde, wave w -> g=w ----
        {
            int g = wv_id;
            float part = sctx[g][l] * sfcW[l] + sctx[g][l + 64] * sfcW[l + 64];
            #pragma unroll
            for (int d = 1; d < 64; d <<= 1) part += __shfl_xor(part, d);
            if (l == 0) {
                float yv = Y[(bbase + g) * TN + t];
                sy[g] = part + yv * sfcW[128] + fcb[0];
            }
        }
        __syncthreads();

        // ---- phase 6: gates = y~*W_ih + d @ W_hhT + (b_ih+b_hh) ----
        float acc[2][4];
        #pragma unroll
        for (int gp = 0; gp < 2; ++gp) {
            float yt = sy[gg + 2 * gp];
            #pragma unroll
            for (int q = 0; q < 4; ++q)
                acc[gp][q] = fmaf(yt, sWih[q * 128 + f], sbsum[q * 128 + f]);
        }
        #pragma unroll 4
        for (int k = 0; k < 128; ++k) {
            float w0 = WT[k * 512 + f];
            float w1 = WT[k * 512 + 128 + f];
            float w2 = WT[k * 512 + 256 + f];
            float w3 = WT[k * 512 + 384 + f];
            #pragma unroll
            for (int gp = 0; gp < 2; ++gp) {
                float dk = sdc[gg + 2 * gp][k];
                acc[gp][0] = fmaf(dk, w0, acc[gp][0]);
                acc[gp][1] = fmaf(dk, w1, acc[gp][1]);
                acc[gp][2] = fmaf(dk, w2, acc[gp][2]);
                acc[gp][3] = fmaf(dk, w3, acc[gp][3]);
            }
        }
        __syncthreads();   // protect old-d reads before overwrite

        // ---- phase 7: LSTM cell update (gate order i,f,g,o) ----
        #pragma unroll
        for (int gp = 0; gp < 2; ++gp) {
            int g = gg + 2 * gp;
            float ig = fast_sigmoid(acc[gp][0]);
            float fg = fast_sigmoid(acc[gp][1]);
            float gt = fast_tanh(acc[gp][2]);
            float og = fast_sigmoid(acc[gp][3]);
            float cn = fg * sdc[g][128 + f] + ig * gt;
            sdc[g][f] = og * fast_tanh(cn);
            sdc[g][128 + f] = cn;
        }
        __syncthreads();   // new d,c visible for next step
    }

    // ---- epilogue: y_pred = [d, ctx] @ fcf_W + fcf_b, wave w -> g=w ----
    {
        int g = wv_id;
        float part = sdc[g][l] * fcfW[l] + sdc[g][l + 64] * fcfW[l + 64]
                   + sctx[g][l] * fcfW[128 + l] + sctx[g][l + 64] * fcfW[192 + l];
        #pragma unroll
        for (int d = 1; d < 64; d <<= 1) part += __shfl_xor(part, d);
        if (l == 0) out[bbase + g] = part + fcfb[0];
    }
}

extern "C" void kernel_launch(void* const* d_in, const int* in_sizes, int n_in,
                              void* d_out, int out_size, void* d_ws, size_t ws_size,
                              hipStream_t stream) {
    const float* H    = (const float*)d_in[0];
    const float* Y    = (const float*)d_in[1];
    const float* W1   = (const float*)d_in[2];
    const float* b1   = (const float*)d_in[3];
    const float* W2   = (const float*)d_in[4];
    // d_in[5] = attn_b2: softmax-invariant, unused
    const float* Wih  = (const float*)d_in[6];
    const float* Whh  = (const float*)d_in[7];
    const float* bih  = (const float*)d_in[8];
    const float* bhh  = (const float*)d_in[9];
    const float* fcW  = (const float*)d_in[10];
    const float* fcb  = (const float*)d_in[11];
    const float* fcfW = (const float*)d_in[12];
    const float* fcfb = (const float*)d_in[13];

    float* HW = (float*)d_ws;                       // 2048*64*128 floats = 64 MB
    float* WT = HW + (size_t)BN * TN * FEATN;       // 128*512 floats
    float* out = (float*)d_out;

    precompute_hw<<<BN * TN / 16, 256, 0, stream>>>(H, W1, b1, HW);
    transpose_whh<<<(512 * 128) / 256, 256, 0, stream>>>(Whh, WT);
    decoder_scan<<<NBLK, 256, 0, stream>>>(H, Y, W1, W2, Wih, bih, bhh,
                                           fcW, fcb, fcfW, fcfb, HW, WT, out);
}